// Round 1
// baseline (3183.363 us; speedup 1.0000x reference)
//
#include <hip/hip_runtime.h>
#include <hip/hip_bf16.h>
#include <cstdint>
#include <cstddef>

typedef __bf16 bf16_t;
typedef bf16_t bf16x8 __attribute__((ext_vector_type(8)));
typedef float f32x4 __attribute__((ext_vector_type(4)));

#define EPS_P 1e-4
#define RMS_EPS_D 1e-5

// ---------- async global->LDS 16B (wave-uniform LDS base + lane*16) ----------
__device__ __forceinline__ void async_cp16(const void* g, void* l) {
  __builtin_amdgcn_global_load_lds(
      (const __attribute__((address_space(1))) unsigned int*)g,
      (__attribute__((address_space(3))) unsigned int*)l, 16, 0, 0);
}

// ---------------- transpose + cast fp32[R][C] -> bf16[C][R] ----------------
__global__ __launch_bounds__(256) void transpose_cast(
    const float* __restrict__ in, bf16_t* __restrict__ out, int R, int C) {
  __shared__ float tile[32][33];
  int c0 = blockIdx.x * 32, r0 = blockIdx.y * 32;
  int tx = threadIdx.x & 31, ty = threadIdx.x >> 5;  // 32x8
#pragma unroll
  for (int s = 0; s < 4; ++s) {
    int r = ty + s * 8;
    tile[r][tx] = in[(size_t)(r0 + r) * C + c0 + tx];
  }
  __syncthreads();
#pragma unroll
  for (int s = 0; s < 4; ++s) {
    int cc = ty + s * 8;
    out[(size_t)(c0 + cc) * R + r0 + tx] = (bf16_t)tile[tx][cc];
  }
}

// ---------------- RMSNorm (fp64 accum) + cast to bf16 ----------------
__global__ __launch_bounds__(256) void rmsnorm_cast(
    const float* __restrict__ X, const float* __restrict__ Wn,
    bf16_t* __restrict__ Xn, int d) {
  int row = blockIdx.x;
  const float* xr = X + (size_t)row * d;
  int t = threadIdx.x, l = t & 63, w = t >> 6;
  double ss = 0.0;
  for (int c = t * 4; c < d; c += 1024) {
    float4 v = *(const float4*)(xr + c);
    ss += (double)v.x * v.x + (double)v.y * v.y + (double)v.z * v.z + (double)v.w * v.w;
  }
#pragma unroll
  for (int o = 32; o > 0; o >>= 1) ss += __shfl_down(ss, o, 64);
  __shared__ double red[4];
  if (l == 0) red[w] = ss;
  __syncthreads();
  double tot = red[0] + red[1] + red[2] + red[3];
  float inv = (float)(1.0 / sqrt(tot / (double)d + RMS_EPS_D));
  for (int c = t * 4; c < d; c += 1024) {
    float4 v = *(const float4*)(xr + c);
    float4 wv = *(const float4*)(Wn + c);
    bf16_t* o = Xn + (size_t)row * d + c;
    o[0] = (bf16_t)(v.x * inv * wv.x);
    o[1] = (bf16_t)(v.y * inv * wv.y);
    o[2] = (bf16_t)(v.z * inv * wv.z);
    o[3] = (bf16_t)(v.w * inv * wv.w);
  }
}

// ---------------- fp32 GEMM  C[M,N] = A[M,K] @ B[K,N]  (128x128x16, 8x8 micro) ----------------
__global__ __launch_bounds__(256) void gemm_f32(
    const float* __restrict__ A, const float* __restrict__ B,
    float* __restrict__ C, int M, int N, int K) {
  __shared__ float Ast[16][132];  // transposed A tile [k][m], padded
  __shared__ float Bs[16][132];
  const int t = threadIdx.x;
  const int m0 = blockIdx.y * 128, n0 = blockIdx.x * 128;
  const int ty = t >> 4, tx = t & 15;
  float acc[8][8] = {};
  for (int k0 = 0; k0 < K; k0 += 16) {
    __syncthreads();
#pragma unroll
    for (int qq = 0; qq < 2; ++qq) {
      int c = t * 2 + qq;          // 0..511
      int row = c >> 2;            // 0..127
      int kq = (c & 3) << 2;       // 0,4,8,12
      float4 v = *(const float4*)(A + (size_t)(m0 + row) * K + k0 + kq);
      Ast[kq + 0][row] = v.x; Ast[kq + 1][row] = v.y;
      Ast[kq + 2][row] = v.z; Ast[kq + 3][row] = v.w;
    }
#pragma unroll
    for (int qq = 0; qq < 2; ++qq) {
      int c = t * 2 + qq;
      int row = c >> 5;            // 0..15
      int n4 = (c & 31) << 2;      // 0..124
      *(float4*)&Bs[row][n4] = *(const float4*)(B + (size_t)(k0 + row) * N + n0 + n4);
    }
    __syncthreads();
#pragma unroll
    for (int kk = 0; kk < 16; ++kk) {
      float a[8], b[8];
      *(float4*)&a[0] = *(const float4*)&Ast[kk][ty * 8];
      *(float4*)&a[4] = *(const float4*)&Ast[kk][ty * 8 + 4];
      *(float4*)&b[0] = *(const float4*)&Bs[kk][tx * 8];
      *(float4*)&b[4] = *(const float4*)&Bs[kk][tx * 8 + 4];
#pragma unroll
      for (int i = 0; i < 8; ++i)
#pragma unroll
        for (int j = 0; j < 8; ++j)
          acc[i][j] = fmaf(a[i], b[j], acc[i][j]);
    }
  }
#pragma unroll
  for (int i = 0; i < 8; ++i) {
    float* Cr = C + (size_t)(m0 + ty * 8 + i) * N + n0 + tx * 8;
    *(float4*)Cr = *(const float4*)&acc[i][0];
    *(float4*)(Cr + 4) = *(const float4*)&acc[i][4];
  }
}

// ---------------- cos / p / a / b per token (fp64 accum dots) ----------------
__global__ __launch_bounds__(256) void cos_p(
    const float* __restrict__ Q, const float* __restrict__ Km,
    const int* __restrict__ cu, int ncu,
    float* __restrict__ P, float* __restrict__ Aarr, float* __restrict__ Bf,
    int d) {
  int tk = blockIdx.x;
  int t = threadIdx.x, l = t & 63, w = t >> 6;
  __shared__ double rqk[4], rqq[4], rkk[4];
  double s_qk = 0, s_qq = 0, s_kk = 0;
  if (tk > 0) {
    const float* qr = Q + (size_t)(tk - 1) * d;
    const float* kr = Km + (size_t)tk * d;
    for (int c = t * 4; c < d; c += 1024) {
      float4 qv = *(const float4*)(qr + c);
      float4 kv = *(const float4*)(kr + c);
      s_qk += (double)qv.x * kv.x + (double)qv.y * kv.y + (double)qv.z * kv.z + (double)qv.w * kv.w;
      s_qq += (double)qv.x * qv.x + (double)qv.y * qv.y + (double)qv.z * qv.z + (double)qv.w * qv.w;
      s_kk += (double)kv.x * kv.x + (double)kv.y * kv.y + (double)kv.z * kv.z + (double)kv.w * kv.w;
    }
#pragma unroll
    for (int o = 32; o > 0; o >>= 1) {
      s_qk += __shfl_down(s_qk, o, 64);
      s_qq += __shfl_down(s_qq, o, 64);
      s_kk += __shfl_down(s_kk, o, 64);
    }
    if (l == 0) { rqk[w] = s_qk; rqq[w] = s_qq; rkk[w] = s_kk; }
    __syncthreads();
  }
  if (t == 0) {
    bool start = false;
    for (int i = 0; i + 1 < ncu; ++i)
      if (cu[i] == tk) start = true;
    double p;
    if (tk == 0) {
      p = 1.0;
    } else {
      double dqk = rqk[0] + rqk[1] + rqk[2] + rqk[3];
      double dqq = rqq[0] + rqq[1] + rqq[2] + rqq[3];
      double dkk = rkk[0] + rkk[1] + rkk[2] + rkk[3];
      double cosv = dqk / sqrt(dqq * dkk);
      p = (1.0 - cosv) * 0.5;
    }
    if (start) p = 1.0;
    if (p < EPS_P) p = EPS_P;
    if (p > 1.0 - EPS_P) p = 1.0 - EPS_P;
    float b = (p >= 0.5) ? 1.0f : 0.0f;
    float a = start ? 0.0f : ((b > 0.5f) ? (float)(1.0 - p) : 1.0f);
    P[tk] = (float)p; Aarr[tk] = a; Bf[tk] = b;
  }
}

// ---------------- intra-chunk prefix products of a (chunk = 64) ----------------
__global__ void pfx_kernel(const float* __restrict__ Aarr, float* __restrict__ Pfx,
                           float* __restrict__ Ac, int T) {
  int c = threadIdx.x;
  if (c * 64 < T) {
    float Pv = 1.0f;
    for (int i = 0; i < 64; ++i) {
      int tt = c * 64 + i;
      Pv *= Aarr[tt];
      Pfx[tt] = Pv;
    }
    Ac[c] = Pv;
  }
}

// ---------------- bf16 MFMA GEMM (128x128x32) + residual epilogue ----------------
// Z[M,N] = X[M,N] + A[M,K] @ Bt[N,K]^T     (A,Bt k-contiguous bf16)
__global__ __launch_bounds__(256) void gemm_bf16_res(
    const bf16_t* __restrict__ A, const bf16_t* __restrict__ Bt,
    const float* __restrict__ X, float* __restrict__ Z,
    int M, int N, int K) {
  __shared__ bf16_t As[128 * 32];
  __shared__ bf16_t Bs[128 * 32];
  const int t = threadIdx.x, w = t >> 6, l = t & 63;
  const int m0 = blockIdx.y * 128, n0 = blockIdx.x * 128;
  const int wr = (w >> 1) * 64, wc = (w & 1) * 64;
  f32x4 acc[4][4] = {};
  // staging chunks: chunk id = (w*2+issue)*64 + lane; row=c>>2, koff=(c&3)*8 elems
  const int ca0 = (w * 2) * 64 + l, ca1 = ca0 + 64;
  const int r0 = ca0 >> 2, ko0 = (ca0 & 3) * 8;
  const int r1 = ca1 >> 2, ko1 = (ca1 & 3) * 8;
  const int a_off = (wr + (l & 15)) * 32 + (l >> 4) * 8;
  const int b_off = (wc + (l & 15)) * 32 + (l >> 4) * 8;
  for (int k0 = 0; k0 < K; k0 += 32) {
    __syncthreads();
    async_cp16(A + (size_t)(m0 + r0) * K + k0 + ko0, As + (w * 2 + 0) * 512);
    async_cp16(A + (size_t)(m0 + r1) * K + k0 + ko1, As + (w * 2 + 1) * 512);
    async_cp16(Bt + (size_t)(n0 + r0) * K + k0 + ko0, Bs + (w * 2 + 0) * 512);
    async_cp16(Bt + (size_t)(n0 + r1) * K + k0 + ko1, Bs + (w * 2 + 1) * 512);
    __syncthreads();
    bf16x8 af[4], bf[4];
#pragma unroll
    for (int i = 0; i < 4; ++i) af[i] = *(const bf16x8*)(As + a_off + i * 512);
#pragma unroll
    for (int j = 0; j < 4; ++j) bf[j] = *(const bf16x8*)(Bs + b_off + j * 512);
#pragma unroll
    for (int i = 0; i < 4; ++i)
#pragma unroll
      for (int j = 0; j < 4; ++j)
        acc[i][j] = __builtin_amdgcn_mfma_f32_16x16x32_bf16(af[i], bf[j], acc[i][j], 0, 0, 0);
  }
  const int col_l = l & 15, row_q = (l >> 4) * 4;
#pragma unroll
  for (int i = 0; i < 4; ++i)
#pragma unroll
    for (int j = 0; j < 4; ++j) {
      int col = n0 + wc + j * 16 + col_l;
#pragma unroll
      for (int r = 0; r < 4; ++r) {
        int row = m0 + wr + i * 16 + row_q + r;
        size_t idx = (size_t)row * N + col;
        Z[idx] = X[idx] + acc[i][j][r];
      }
    }
}

// ---------------- bf16 MFMA GEMM with fused SwiGLU (tile 128 x 64-u-cols) ----------------
// U[M,Nu] = silu(A@Bg^T) * (A@Bh^T);  Bh = fc1t rows [n], Bg = fc1t rows [H+n]
__global__ __launch_bounds__(256) void gemm_bf16_swiglu(
    const bf16_t* __restrict__ A, const bf16_t* __restrict__ B1t,
    bf16_t* __restrict__ U, int M, int Nu, int K, int H) {
  __shared__ bf16_t As[128 * 32];
  __shared__ bf16_t Bs[128 * 32];  // rows 0..63 = hh half, rows 64..127 = g half
  const int t = threadIdx.x, w = t >> 6, l = t & 63;
  const int m0 = blockIdx.y * 128, n0 = blockIdx.x * 64;
  const int wr = (w >> 1) * 64, wc = (w & 1) * 32;
  f32x4 acch[4][2] = {}, accg[4][2] = {};
  const int ca0 = (w * 2) * 64 + l, ca1 = ca0 + 64;
  const int r0 = ca0 >> 2, ko0 = (ca0 & 3) * 8;
  const int r1 = ca1 >> 2, ko1 = (ca1 & 3) * 8;
  const bf16_t* bh = B1t + (size_t)n0 * K;
  const bf16_t* bg = B1t + (size_t)(H + n0) * K;
  const bf16_t* bp0 = (r0 < 64) ? bh + (size_t)r0 * K : bg + (size_t)(r0 - 64) * K;
  const bf16_t* bp1 = (r1 < 64) ? bh + (size_t)r1 * K : bg + (size_t)(r1 - 64) * K;
  const int a_off = (wr + (l & 15)) * 32 + (l >> 4) * 8;
  const int bh_off = (wc + (l & 15)) * 32 + (l >> 4) * 8;
  for (int k0 = 0; k0 < K; k0 += 32) {
    __syncthreads();
    async_cp16(A + (size_t)(m0 + r0) * K + k0 + ko0, As + (w * 2 + 0) * 512);
    async_cp16(A + (size_t)(m0 + r1) * K + k0 + ko1, As + (w * 2 + 1) * 512);
    async_cp16(bp0 + k0 + ko0, Bs + (w * 2 + 0) * 512);
    async_cp16(bp1 + k0 + ko1, Bs + (w * 2 + 1) * 512);
    __syncthreads();
    bf16x8 af[4], bfh[2], bfg[2];
#pragma unroll
    for (int i = 0; i < 4; ++i) af[i] = *(const bf16x8*)(As + a_off + i * 512);
#pragma unroll
    for (int j = 0; j < 2; ++j) {
      bfh[j] = *(const bf16x8*)(Bs + bh_off + j * 512);
      bfg[j] = *(const bf16x8*)(Bs + bh_off + 64 * 32 + j * 512);
    }
#pragma unroll
    for (int i = 0; i < 4; ++i)
#pragma unroll
      for (int j = 0; j < 2; ++j) {
        acch[i][j] = __builtin_amdgcn_mfma_f32_16x16x32_bf16(af[i], bfh[j], acch[i][j], 0, 0, 0);
        accg[i][j] = __builtin_amdgcn_mfma_f32_16x16x32_bf16(af[i], bfg[j], accg[i][j], 0, 0, 0);
      }
  }
  const int col_l = l & 15, row_q = (l >> 4) * 4;
#pragma unroll
  for (int i = 0; i < 4; ++i)
#pragma unroll
    for (int j = 0; j < 2; ++j) {
      int col = n0 + wc + j * 16 + col_l;
#pragma unroll
      for (int r = 0; r < 4; ++r) {
        int row = m0 + wr + i * 16 + row_q + r;
        float g = accg[i][j][r];
        float hh = acch[i][j][r];
        float s = g / (1.0f + expf(-g));
        U[(size_t)row * Nu + col] = (bf16_t)(s * hh);
      }
    }
}

// ---------------- scan pass 1: per-chunk local scan, in-place on Z (d_out) ----------------
__global__ __launch_bounds__(256) void scan1(
    float* __restrict__ Z, const float* __restrict__ P,
    const float* __restrict__ Aarr, const float* __restrict__ Bf, int d) {
  int c = blockIdx.x;
  int col = blockIdx.y * 512 + threadIdx.x * 2;
  __shared__ float sa[64], sp[64], sb[64];
  if (threadIdx.x < 64) {
    int tt = c * 64 + threadIdx.x;
    sa[threadIdx.x] = Aarr[tt];
    sp[threadIdx.x] = P[tt];
    sb[threadIdx.x] = Bf[tt];
  }
  __syncthreads();
  float hx = 0.0f, hy = 0.0f;
  for (int i = 0; i < 64; ++i) {
    int row = c * 64 + i;
    float a = sa[i];
    float2* zp = (float2*)(Z + (size_t)row * d + col);
    if (sb[i] > 0.5f) {
      float2 zv = *zp;
      float pp = sp[i];
      hx = a * hx + pp * zv.x;
      hy = a * hy + pp * zv.y;
    } else {
      hx = a * hx;
      hy = a * hy;
    }
    float2 hv; hv.x = hx; hv.y = hy;
    *zp = hv;
  }
}

// ---------------- scan pass 2: chunk-level carry scan ----------------
__global__ __launch_bounds__(256) void scan2(
    const float* __restrict__ Z, const float* __restrict__ Ac,
    float* __restrict__ Hprev, int d, int NC) {
  int col = blockIdx.x * 256 + threadIdx.x;
  float H = 0.0f;
  for (int c = 0; c < NC; ++c) {
    Hprev[(size_t)c * d + col] = H;
    float E = Z[(size_t)(c * 64 + 63) * d + col];
    H = Ac[c] * H + E;
  }
}

// ---------------- scan pass 3: add carry * intra-chunk prefix ----------------
__global__ __launch_bounds__(256) void scan3(
    float* __restrict__ Z, const float* __restrict__ Pfx,
    const float* __restrict__ Hprev, int d) {
  int row = blockIdx.x;
  int c = row >> 6;
  float pf = Pfx[row];
  int col = threadIdx.x * 8;
  const float* hp = Hprev + (size_t)c * d + col;
  float4 h0 = *(const float4*)hp;
  float4 h1 = *(const float4*)(hp + 4);
  float* zp = Z + (size_t)row * d + col;
  float4 z0 = *(const float4*)zp;
  float4 z1 = *(const float4*)(zp + 4);
  z0.x += pf * h0.x; z0.y += pf * h0.y; z0.z += pf * h0.z; z0.w += pf * h0.w;
  z1.x += pf * h1.x; z1.y += pf * h1.y; z1.z += pf * h1.z; z1.w += pf * h1.w;
  *(float4*)zp = z0;
  *(float4*)(zp + 4) = z1;
}

// ---------------- host ----------------
extern "C" void kernel_launch(void* const* d_in, const int* in_sizes, int n_in,
                              void* d_out, int out_size, void* d_ws, size_t ws_size,
                              hipStream_t stream) {
  const float* x   = (const float*)d_in[0];
  const float* Wq  = (const float*)d_in[1];
  const float* Wk  = (const float*)d_in[2];
  const float* fc1 = (const float*)d_in[3];
  const float* fc2 = (const float*)d_in[4];
  const float* nw  = (const float*)d_in[5];
  const int*   cu  = (const int*)d_in[6];
  const int ncu = in_sizes[6];
  const int d = in_sizes[5];            // 2048
  const int T = in_sizes[0] / d;        // 8192
  const int h = in_sizes[4] / d;        // 8192
  const int NC = T / 64;                // 128 chunks
  float* zout = (float*)d_out;

  char* ws = (char*)d_ws;
  size_t off = 0;
  auto alloc = [&](size_t bytes) -> void* {
    void* p = ws + off;
    off += (bytes + 255) & ~(size_t)255;
    return p;
  };
  float*  q    = (float*)alloc((size_t)T * d * 4);
  float*  k    = (float*)alloc((size_t)T * d * 4);
  bf16_t* u    = (bf16_t*)q;  // reuse q+k region after cos_p (T*h*2 == 2*T*d*4)
  bf16_t* xn   = (bf16_t*)alloc((size_t)T * d * 2);
  bf16_t* fc1t = (bf16_t*)alloc((size_t)2 * h * d * 2);
  bf16_t* fc2t = (bf16_t*)alloc((size_t)h * d * 2);
  float*  P    = (float*)alloc((size_t)T * 4);
  float*  Aa   = (float*)alloc((size_t)T * 4);
  float*  Bf   = (float*)alloc((size_t)T * 4);
  float*  Pfx  = (float*)alloc((size_t)T * 4);
  float*  Ac   = (float*)alloc((size_t)NC * 4);
  float*  Hprev= (float*)alloc((size_t)NC * d * 4);

  // weight transposes + casts (independent)
  transpose_cast<<<dim3(2 * h / 32, d / 32), 256, 0, stream>>>(fc1, fc1t, d, 2 * h);
  transpose_cast<<<dim3(d / 32, h / 32), 256, 0, stream>>>(fc2, fc2t, h, d);
  // rmsnorm + bf16 cast
  rmsnorm_cast<<<dim3(T), 256, 0, stream>>>(x, nw, xn, d);
  // q,k projections (fp32 for boundary precision)
  gemm_f32<<<dim3(d / 128, T / 128), 256, 0, stream>>>(x, Wq, q, T, d, d);
  gemm_f32<<<dim3(d / 128, T / 128), 256, 0, stream>>>(x, Wk, k, T, d, d);
  // boundary probabilities
  cos_p<<<dim3(T), 256, 0, stream>>>(q, k, cu, ncu, P, Aa, Bf, d);
  pfx_kernel<<<dim3(1), 128, 0, stream>>>(Aa, Pfx, Ac, T);
  // MLP (q,k dead now; u reuses their space)
  gemm_bf16_swiglu<<<dim3(h / 64, T / 128), 256, 0, stream>>>(xn, fc1t, u, T, h, d, h);
  gemm_bf16_res<<<dim3(d / 128, T / 128), 256, 0, stream>>>(u, fc2t, x, zout, T, d, h);
  // EMA scan (3 passes, in place on d_out)
  scan1<<<dim3(NC, d / 512), 256, 0, stream>>>(zout, P, Aa, Bf, d);
  scan2<<<dim3(d / 256), 256, 0, stream>>>(zout, Ac, Hprev, d, NC);
  scan3<<<dim3(T), 256, 0, stream>>>(zout, Pfx, Hprev, d);
}

// Round 2
// 1933.998 us; speedup vs baseline: 1.6460x; 1.6460x over previous
//
#include <hip/hip_runtime.h>
#include <hip/hip_bf16.h>
#include <cstdint>
#include <cstddef>

typedef __bf16 bf16_t;
typedef bf16_t bf16x8 __attribute__((ext_vector_type(8)));
typedef _Float16 f16_t;
typedef f16_t f16x8 __attribute__((ext_vector_type(8)));
typedef float f32x4 __attribute__((ext_vector_type(4)));

#define EPS_P 1e-4
#define RMS_EPS_D 1e-5
#define WSCALE 64.0f

// ---------- async global->LDS 16B (wave-uniform LDS base + lane*16) ----------
__device__ __forceinline__ void async_cp16(const void* g, void* l) {
  __builtin_amdgcn_global_load_lds(
      (const __attribute__((address_space(1))) unsigned int*)g,
      (__attribute__((address_space(3))) unsigned int*)l, 16, 0, 0);
}

// ---------------- transpose + cast fp32[R][C] -> bf16[C][R] ----------------
__global__ __launch_bounds__(256) void transpose_cast(
    const float* __restrict__ in, bf16_t* __restrict__ out, int R, int C) {
  __shared__ float tile[32][33];
  int c0 = blockIdx.x * 32, r0 = blockIdx.y * 32;
  int tx = threadIdx.x & 31, ty = threadIdx.x >> 5;  // 32x8
#pragma unroll
  for (int s = 0; s < 4; ++s) {
    int r = ty + s * 8;
    tile[r][tx] = in[(size_t)(r0 + r) * C + c0 + tx];
  }
  __syncthreads();
#pragma unroll
  for (int s = 0; s < 4; ++s) {
    int cc = ty + s * 8;
    out[(size_t)(c0 + cc) * R + r0 + tx] = (bf16_t)tile[tx][cc];
  }
}

// ------- transpose + scale + split fp32[R][C] -> fp16 hi/lo [C][R] -------
__global__ __launch_bounds__(256) void transpose_split(
    const float* __restrict__ in, f16_t* __restrict__ oh, f16_t* __restrict__ ol,
    int R, int C) {
  __shared__ float tile[32][33];
  int c0 = blockIdx.x * 32, r0 = blockIdx.y * 32;
  int tx = threadIdx.x & 31, ty = threadIdx.x >> 5;
#pragma unroll
  for (int s = 0; s < 4; ++s) {
    int r = ty + s * 8;
    tile[r][tx] = in[(size_t)(r0 + r) * C + c0 + tx];
  }
  __syncthreads();
#pragma unroll
  for (int s = 0; s < 4; ++s) {
    int cc = ty + s * 8;
    float v = tile[tx][cc] * WSCALE;
    f16_t hi = (f16_t)v;
    f16_t lo = (f16_t)(v - (float)hi);
    size_t idx = (size_t)(c0 + cc) * R + r0 + tx;
    oh[idx] = hi;
    ol[idx] = lo;
  }
}

// ---------------- elementwise split fp32 -> fp16 hi/lo ----------------
__global__ __launch_bounds__(256) void split_x(
    const float* __restrict__ x, f16_t* __restrict__ xh, f16_t* __restrict__ xl,
    int n4) {
  int i = blockIdx.x * 256 + threadIdx.x;
  if (i >= n4) return;
  float4 v = *(const float4*)(x + (size_t)i * 4);
  f16_t h0 = (f16_t)v.x, h1 = (f16_t)v.y, h2 = (f16_t)v.z, h3 = (f16_t)v.w;
  f16_t hv[4] = {h0, h1, h2, h3};
  f16_t lv[4] = {(f16_t)(v.x - (float)h0), (f16_t)(v.y - (float)h1),
                 (f16_t)(v.z - (float)h2), (f16_t)(v.w - (float)h3)};
  *(f16x8*)0;  // (unused)
  *(short4*)(xh + (size_t)i * 4) = *(short4*)hv;
  *(short4*)(xl + (size_t)i * 4) = *(short4*)lv;
}

// ---------------- RMSNorm (fp64 accum) + cast to bf16 ----------------
__global__ __launch_bounds__(256) void rmsnorm_cast(
    const float* __restrict__ X, const float* __restrict__ Wn,
    bf16_t* __restrict__ Xn, int d) {
  int row = blockIdx.x;
  const float* xr = X + (size_t)row * d;
  int t = threadIdx.x, l = t & 63, w = t >> 6;
  double ss = 0.0;
  for (int c = t * 4; c < d; c += 1024) {
    float4 v = *(const float4*)(xr + c);
    ss += (double)v.x * v.x + (double)v.y * v.y + (double)v.z * v.z + (double)v.w * v.w;
  }
#pragma unroll
  for (int o = 32; o > 0; o >>= 1) ss += __shfl_down(ss, o, 64);
  __shared__ double red[4];
  if (l == 0) red[w] = ss;
  __syncthreads();
  double tot = red[0] + red[1] + red[2] + red[3];
  float inv = (float)(1.0 / sqrt(tot / (double)d + RMS_EPS_D));
  for (int c = t * 4; c < d; c += 1024) {
    float4 v = *(const float4*)(xr + c);
    float4 wv = *(const float4*)(Wn + c);
    bf16_t* o = Xn + (size_t)row * d + c;
    o[0] = (bf16_t)(v.x * inv * wv.x);
    o[1] = (bf16_t)(v.y * inv * wv.y);
    o[2] = (bf16_t)(v.z * inv * wv.z);
    o[3] = (bf16_t)(v.w * inv * wv.w);
  }
}

// ------- fp16-split MFMA GEMM: Out[M,N] = (Ah+Al)[M,K] @ (Bh+Bl)[N,K]^T * outscale
// (drops Al*Bl term; single accumulator since all terms share exact scale) -------
__global__ __launch_bounds__(256) void gemm_f16_split(
    const f16_t* __restrict__ Ahg, const f16_t* __restrict__ Alg,
    const f16_t* __restrict__ Bhg, const f16_t* __restrict__ Blg,
    float* __restrict__ Out, int M, int N, int K, float outscale) {
  __shared__ f16_t Ah[128 * 32], Al[128 * 32], Bh[128 * 32], Bl[128 * 32];
  const int t = threadIdx.x, w = t >> 6, l = t & 63;
  const int m0 = blockIdx.y * 128, n0 = blockIdx.x * 128;
  const int wr = (w >> 1) * 64, wc = (w & 1) * 64;
  f32x4 acc[4][4] = {};
  const int ca0 = (w * 2) * 64 + l, ca1 = ca0 + 64;
  const int r0 = ca0 >> 2, ko0 = (ca0 & 3) * 8;
  const int r1 = ca1 >> 2, ko1 = (ca1 & 3) * 8;
  const int a_off = (wr + (l & 15)) * 32 + (l >> 4) * 8;
  const int b_off = (wc + (l & 15)) * 32 + (l >> 4) * 8;
  for (int k0 = 0; k0 < K; k0 += 32) {
    __syncthreads();
    async_cp16(Ahg + (size_t)(m0 + r0) * K + k0 + ko0, Ah + (w * 2 + 0) * 512);
    async_cp16(Ahg + (size_t)(m0 + r1) * K + k0 + ko1, Ah + (w * 2 + 1) * 512);
    async_cp16(Alg + (size_t)(m0 + r0) * K + k0 + ko0, Al + (w * 2 + 0) * 512);
    async_cp16(Alg + (size_t)(m0 + r1) * K + k0 + ko1, Al + (w * 2 + 1) * 512);
    async_cp16(Bhg + (size_t)(n0 + r0) * K + k0 + ko0, Bh + (w * 2 + 0) * 512);
    async_cp16(Bhg + (size_t)(n0 + r1) * K + k0 + ko1, Bh + (w * 2 + 1) * 512);
    async_cp16(Blg + (size_t)(n0 + r0) * K + k0 + ko0, Bl + (w * 2 + 0) * 512);
    async_cp16(Blg + (size_t)(n0 + r1) * K + k0 + ko1, Bl + (w * 2 + 1) * 512);
    __syncthreads();
    f16x8 ah[4], al[4], bh[4], bl[4];
#pragma unroll
    for (int i = 0; i < 4; ++i) {
      ah[i] = *(const f16x8*)(Ah + a_off + i * 512);
      al[i] = *(const f16x8*)(Al + a_off + i * 512);
    }
#pragma unroll
    for (int j = 0; j < 4; ++j) {
      bh[j] = *(const f16x8*)(Bh + b_off + j * 512);
      bl[j] = *(const f16x8*)(Bl + b_off + j * 512);
    }
#pragma unroll
    for (int i = 0; i < 4; ++i)
#pragma unroll
      for (int j = 0; j < 4; ++j) {
        acc[i][j] = __builtin_amdgcn_mfma_f32_16x16x32_f16(ah[i], bh[j], acc[i][j], 0, 0, 0);
        acc[i][j] = __builtin_amdgcn_mfma_f32_16x16x32_f16(ah[i], bl[j], acc[i][j], 0, 0, 0);
        acc[i][j] = __builtin_amdgcn_mfma_f32_16x16x32_f16(al[i], bh[j], acc[i][j], 0, 0, 0);
      }
  }
  const int col_l = l & 15, row_q = (l >> 4) * 4;
#pragma unroll
  for (int i = 0; i < 4; ++i)
#pragma unroll
    for (int j = 0; j < 4; ++j) {
      int col = n0 + wc + j * 16 + col_l;
#pragma unroll
      for (int r = 0; r < 4; ++r) {
        int row = m0 + wr + i * 16 + row_q + r;
        Out[(size_t)row * N + col] = acc[i][j][r] * outscale;
      }
    }
}

// ---------------- cos / p / a / b per token (fp64 accum dots) ----------------
// QK layout: [T, 4096], q_t = QK[t, 0:2048], k_t = QK[t, 2048:4096]
__global__ __launch_bounds__(256) void cos_p(
    const float* __restrict__ QK,
    const int* __restrict__ cu, int ncu,
    float* __restrict__ P, float* __restrict__ Aarr, float* __restrict__ Bf,
    int d) {
  int tk = blockIdx.x;
  int t = threadIdx.x, l = t & 63, w = t >> 6;
  __shared__ double rqk[4], rqq[4], rkk[4];
  double s_qk = 0, s_qq = 0, s_kk = 0;
  if (tk > 0) {
    const float* qr = QK + (size_t)(tk - 1) * (2 * d);
    const float* kr = QK + (size_t)tk * (2 * d) + d;
    for (int c = t * 4; c < d; c += 1024) {
      float4 qv = *(const float4*)(qr + c);
      float4 kv = *(const float4*)(kr + c);
      s_qk += (double)qv.x * kv.x + (double)qv.y * kv.y + (double)qv.z * kv.z + (double)qv.w * kv.w;
      s_qq += (double)qv.x * qv.x + (double)qv.y * qv.y + (double)qv.z * qv.z + (double)qv.w * qv.w;
      s_kk += (double)kv.x * kv.x + (double)kv.y * kv.y + (double)kv.z * kv.z + (double)kv.w * kv.w;
    }
#pragma unroll
    for (int o = 32; o > 0; o >>= 1) {
      s_qk += __shfl_down(s_qk, o, 64);
      s_qq += __shfl_down(s_qq, o, 64);
      s_kk += __shfl_down(s_kk, o, 64);
    }
    if (l == 0) { rqk[w] = s_qk; rqq[w] = s_qq; rkk[w] = s_kk; }
    __syncthreads();
  }
  if (t == 0) {
    bool start = false;
    for (int i = 0; i + 1 < ncu; ++i)
      if (cu[i] == tk) start = true;
    double p;
    if (tk == 0) {
      p = 1.0;
    } else {
      double dqk = rqk[0] + rqk[1] + rqk[2] + rqk[3];
      double dqq = rqq[0] + rqq[1] + rqq[2] + rqq[3];
      double dkk = rkk[0] + rkk[1] + rkk[2] + rkk[3];
      double cosv = dqk / sqrt(dqq * dkk);
      p = (1.0 - cosv) * 0.5;
    }
    if (start) p = 1.0;
    if (p < EPS_P) p = EPS_P;
    if (p > 1.0 - EPS_P) p = 1.0 - EPS_P;
    float b = (p >= 0.5) ? 1.0f : 0.0f;
    float a = start ? 0.0f : ((b > 0.5f) ? (float)(1.0 - p) : 1.0f);
    P[tk] = (float)p; Aarr[tk] = a; Bf[tk] = b;
  }
}

// ---------------- intra-chunk prefix products of a (chunk = 64) ----------------
__global__ void pfx_kernel(const float* __restrict__ Aarr, float* __restrict__ Pfx,
                           float* __restrict__ Ac, int T) {
  int c = threadIdx.x;
  if (c * 64 < T) {
    float Pv = 1.0f;
    for (int i = 0; i < 64; ++i) {
      int tt = c * 64 + i;
      Pv *= Aarr[tt];
      Pfx[tt] = Pv;
    }
    Ac[c] = Pv;
  }
}

// ---------------- bf16 MFMA GEMM (128x128x32) + residual epilogue ----------------
// Z[M,N] = X[M,N] + A[M,K] @ Bt[N,K]^T     (A,Bt k-contiguous bf16)
__global__ __launch_bounds__(256) void gemm_bf16_res(
    const bf16_t* __restrict__ A, const bf16_t* __restrict__ Bt,
    const float* __restrict__ X, float* __restrict__ Z,
    int M, int N, int K) {
  __shared__ bf16_t As[128 * 32];
  __shared__ bf16_t Bs[128 * 32];
  const int t = threadIdx.x, w = t >> 6, l = t & 63;
  const int m0 = blockIdx.y * 128, n0 = blockIdx.x * 128;
  const int wr = (w >> 1) * 64, wc = (w & 1) * 64;
  f32x4 acc[4][4] = {};
  const int ca0 = (w * 2) * 64 + l, ca1 = ca0 + 64;
  const int r0 = ca0 >> 2, ko0 = (ca0 & 3) * 8;
  const int r1 = ca1 >> 2, ko1 = (ca1 & 3) * 8;
  const int a_off = (wr + (l & 15)) * 32 + (l >> 4) * 8;
  const int b_off = (wc + (l & 15)) * 32 + (l >> 4) * 8;
  for (int k0 = 0; k0 < K; k0 += 32) {
    __syncthreads();
    async_cp16(A + (size_t)(m0 + r0) * K + k0 + ko0, As + (w * 2 + 0) * 512);
    async_cp16(A + (size_t)(m0 + r1) * K + k0 + ko1, As + (w * 2 + 1) * 512);
    async_cp16(Bt + (size_t)(n0 + r0) * K + k0 + ko0, Bs + (w * 2 + 0) * 512);
    async_cp16(Bt + (size_t)(n0 + r1) * K + k0 + ko1, Bs + (w * 2 + 1) * 512);
    __syncthreads();
    bf16x8 af[4], bf[4];
#pragma unroll
    for (int i = 0; i < 4; ++i) af[i] = *(const bf16x8*)(As + a_off + i * 512);
#pragma unroll
    for (int j = 0; j < 4; ++j) bf[j] = *(const bf16x8*)(Bs + b_off + j * 512);
#pragma unroll
    for (int i = 0; i < 4; ++i)
#pragma unroll
      for (int j = 0; j < 4; ++j)
        acc[i][j] = __builtin_amdgcn_mfma_f32_16x16x32_bf16(af[i], bf[j], acc[i][j], 0, 0, 0);
  }
  const int col_l = l & 15, row_q = (l >> 4) * 4;
#pragma unroll
  for (int i = 0; i < 4; ++i)
#pragma unroll
    for (int j = 0; j < 4; ++j) {
      int col = n0 + wc + j * 16 + col_l;
#pragma unroll
      for (int r = 0; r < 4; ++r) {
        int row = m0 + wr + i * 16 + row_q + r;
        size_t idx = (size_t)row * N + col;
        Z[idx] = X[idx] + acc[i][j][r];
      }
    }
}

// ---------------- bf16 MFMA GEMM with fused SwiGLU (tile 128 x 64-u-cols) ----------------
// U[M,Nu] = silu(A@Bg^T) * (A@Bh^T);  Bh = fc1t rows [n], Bg = fc1t rows [H+n]
__global__ __launch_bounds__(256) void gemm_bf16_swiglu(
    const bf16_t* __restrict__ A, const bf16_t* __restrict__ B1t,
    bf16_t* __restrict__ U, int M, int Nu, int K, int H) {
  __shared__ bf16_t As[128 * 32];
  __shared__ bf16_t Bs[128 * 32];  // rows 0..63 = hh half, rows 64..127 = g half
  const int t = threadIdx.x, w = t >> 6, l = t & 63;
  const int m0 = blockIdx.y * 128, n0 = blockIdx.x * 64;
  const int wr = (w >> 1) * 64, wc = (w & 1) * 32;
  f32x4 acch[4][2] = {}, accg[4][2] = {};
  const int ca0 = (w * 2) * 64 + l, ca1 = ca0 + 64;
  const int r0 = ca0 >> 2, ko0 = (ca0 & 3) * 8;
  const int r1 = ca1 >> 2, ko1 = (ca1 & 3) * 8;
  const bf16_t* bh = B1t + (size_t)n0 * K;
  const bf16_t* bg = B1t + (size_t)(H + n0) * K;
  const bf16_t* bp0 = (r0 < 64) ? bh + (size_t)r0 * K : bg + (size_t)(r0 - 64) * K;
  const bf16_t* bp1 = (r1 < 64) ? bh + (size_t)r1 * K : bg + (size_t)(r1 - 64) * K;
  const int a_off = (wr + (l & 15)) * 32 + (l >> 4) * 8;
  const int bh_off = (wc + (l & 15)) * 32 + (l >> 4) * 8;
  for (int k0 = 0; k0 < K; k0 += 32) {
    __syncthreads();
    async_cp16(A + (size_t)(m0 + r0) * K + k0 + ko0, As + (w * 2 + 0) * 512);
    async_cp16(A + (size_t)(m0 + r1) * K + k0 + ko1, As + (w * 2 + 1) * 512);
    async_cp16(bp0 + k0 + ko0, Bs + (w * 2 + 0) * 512);
    async_cp16(bp1 + k0 + ko1, Bs + (w * 2 + 1) * 512);
    __syncthreads();
    bf16x8 af[4], bfh[2], bfg[2];
#pragma unroll
    for (int i = 0; i < 4; ++i) af[i] = *(const bf16x8*)(As + a_off + i * 512);
#pragma unroll
    for (int j = 0; j < 2; ++j) {
      bfh[j] = *(const bf16x8*)(Bs + bh_off + j * 512);
      bfg[j] = *(const bf16x8*)(Bs + bh_off + 64 * 32 + j * 512);
    }
#pragma unroll
    for (int i = 0; i < 4; ++i)
#pragma unroll
      for (int j = 0; j < 2; ++j) {
        acch[i][j] = __builtin_amdgcn_mfma_f32_16x16x32_bf16(af[i], bfh[j], acch[i][j], 0, 0, 0);
        accg[i][j] = __builtin_amdgcn_mfma_f32_16x16x32_bf16(af[i], bfg[j], accg[i][j], 0, 0, 0);
      }
  }
  const int col_l = l & 15, row_q = (l >> 4) * 4;
#pragma unroll
  for (int i = 0; i < 4; ++i)
#pragma unroll
    for (int j = 0; j < 2; ++j) {
      int col = n0 + wc + j * 16 + col_l;
#pragma unroll
      for (int r = 0; r < 4; ++r) {
        int row = m0 + wr + i * 16 + row_q + r;
        float g = accg[i][j][r];
        float hh = acch[i][j][r];
        float s = g / (1.0f + expf(-g));
        U[(size_t)row * Nu + col] = (bf16_t)(s * hh);
      }
    }
}

// ---------------- scan pass 1: per-chunk local scan, in-place on Z (d_out) ----------------
__global__ __launch_bounds__(256) void scan1(
    float* __restrict__ Z, const float* __restrict__ P,
    const float* __restrict__ Aarr, const float* __restrict__ Bf, int d) {
  int c = blockIdx.x;
  int col = blockIdx.y * 512 + threadIdx.x * 2;
  __shared__ float sa[64], sp[64], sb[64];
  if (threadIdx.x < 64) {
    int tt = c * 64 + threadIdx.x;
    sa[threadIdx.x] = Aarr[tt];
    sp[threadIdx.x] = P[tt];
    sb[threadIdx.x] = Bf[tt];
  }
  __syncthreads();
  float hx = 0.0f, hy = 0.0f;
  for (int i = 0; i < 64; ++i) {
    int row = c * 64 + i;
    float a = sa[i];
    float2* zp = (float2*)(Z + (size_t)row * d + col);
    if (sb[i] > 0.5f) {
      float2 zv = *zp;
      float pp = sp[i];
      hx = a * hx + pp * zv.x;
      hy = a * hy + pp * zv.y;
    } else {
      hx = a * hx;
      hy = a * hy;
    }
    float2 hv; hv.x = hx; hv.y = hy;
    *zp = hv;
  }
}

// ---------------- scan pass 2: chunk-level carry scan ----------------
__global__ __launch_bounds__(256) void scan2(
    const float* __restrict__ Z, const float* __restrict__ Ac,
    float* __restrict__ Hprev, int d, int NC) {
  int col = blockIdx.x * 256 + threadIdx.x;
  float H = 0.0f;
  for (int c = 0; c < NC; ++c) {
    Hprev[(size_t)c * d + col] = H;
    float E = Z[(size_t)(c * 64 + 63) * d + col];
    H = Ac[c] * H + E;
  }
}

// ---------------- scan pass 3: add carry * intra-chunk prefix ----------------
__global__ __launch_bounds__(256) void scan3(
    float* __restrict__ Z, const float* __restrict__ Pfx,
    const float* __restrict__ Hprev, int d) {
  int row = blockIdx.x;
  int c = row >> 6;
  float pf = Pfx[row];
  int col = threadIdx.x * 8;
  const float* hp = Hprev + (size_t)c * d + col;
  float4 h0 = *(const float4*)hp;
  float4 h1 = *(const float4*)(hp + 4);
  float* zp = Z + (size_t)row * d + col;
  float4 z0 = *(const float4*)zp;
  float4 z1 = *(const float4*)(zp + 4);
  z0.x += pf * h0.x; z0.y += pf * h0.y; z0.z += pf * h0.z; z0.w += pf * h0.w;
  z1.x += pf * h1.x; z1.y += pf * h1.y; z1.z += pf * h1.z; z1.w += pf * h1.w;
  *(float4*)zp = z0;
  *(float4*)(zp + 4) = z1;
}

// ---------------- host ----------------
extern "C" void kernel_launch(void* const* d_in, const int* in_sizes, int n_in,
                              void* d_out, int out_size, void* d_ws, size_t ws_size,
                              hipStream_t stream) {
  const float* x   = (const float*)d_in[0];
  const float* Wq  = (const float*)d_in[1];
  const float* Wk  = (const float*)d_in[2];
  const float* fc1 = (const float*)d_in[3];
  const float* fc2 = (const float*)d_in[4];
  const float* nw  = (const float*)d_in[5];
  const int*   cu  = (const int*)d_in[6];
  const int ncu = in_sizes[6];
  const int d = in_sizes[5];            // 2048
  const int T = in_sizes[0] / d;        // 8192
  const int h = in_sizes[4] / d;        // 8192
  const int NC = T / 64;                // 128 chunks
  float* zout = (float*)d_out;

  char* ws = (char*)d_ws;
  size_t off = 0;
  auto alloc = [&](size_t bytes) -> void* {
    void* p = ws + off;
    off += (bytes + 255) & ~(size_t)255;
    return p;
  };
  // qk [T, 2d] fp32; later reused as u [T, h] bf16 (same byte size)
  float*  qk   = (float*)alloc((size_t)T * 2 * d * 4);
  bf16_t* u    = (bf16_t*)qk;
  bf16_t* xn   = (bf16_t*)alloc((size_t)T * d * 2);
  // region A: first {Xh, Xl, Wth, Wtl} (fp16 splits), later {fc1t, fc2t} (bf16)
  // both are exactly 100,663,296 bytes for T=8192, d=2048, h=8192
  size_t szXh = (size_t)T * d * 2;          // 33.5 MB
  size_t szWt = (size_t)2 * d * d * 2;      // 16.8 MB
  char* regionA = (char*)alloc(2 * szXh + 2 * szWt);
  f16_t* Xh  = (f16_t*)regionA;
  f16_t* Xl  = (f16_t*)(regionA + szXh);
  f16_t* Wth = (f16_t*)(regionA + 2 * szXh);
  f16_t* Wtl = (f16_t*)(regionA + 2 * szXh + szWt);
  bf16_t* fc1t = (bf16_t*)regionA;                           // [2h, d]
  bf16_t* fc2t = (bf16_t*)(regionA + (size_t)2 * h * d * 2); // [d, h]
  float*  P    = (float*)alloc((size_t)T * 4);
  float*  Aa   = (float*)alloc((size_t)T * 4);
  float*  Bf   = (float*)alloc((size_t)T * 4);
  float*  Pfx  = (float*)alloc((size_t)T * 4);
  float*  Ac   = (float*)alloc((size_t)NC * 4);
  float*  Hprev= (float*)alloc((size_t)NC * d * 4);

  // ---- routing: q/k projections on matrix cores via fp16 split ----
  split_x<<<dim3(T * d / 1024), 256, 0, stream>>>(x, Xh, Xl, T * d / 4);
  // W^T combined [2d rows, d]: rows 0..d-1 = Wq^T, rows d..2d-1 = Wk^T (scaled x64)
  transpose_split<<<dim3(d / 32, d / 32), 256, 0, stream>>>(Wq, Wth, Wtl, d, d);
  transpose_split<<<dim3(d / 32, d / 32), 256, 0, stream>>>(
      Wk, Wth + (size_t)d * d, Wtl + (size_t)d * d, d, d);
  gemm_f16_split<<<dim3(2 * d / 128, T / 128), 256, 0, stream>>>(
      Xh, Xl, Wth, Wtl, qk, T, 2 * d, d, 1.0f / WSCALE);
  cos_p<<<dim3(T), 256, 0, stream>>>(qk, cu, ncu, P, Aa, Bf, d);
  pfx_kernel<<<dim3(1), 128, 0, stream>>>(Aa, Pfx, Ac, T);

  // ---- MLP weights into region A (splits dead now) ----
  transpose_cast<<<dim3(2 * h / 32, d / 32), 256, 0, stream>>>(fc1, fc1t, d, 2 * h);
  transpose_cast<<<dim3(d / 32, h / 32), 256, 0, stream>>>(fc2, fc2t, h, d);
  rmsnorm_cast<<<dim3(T), 256, 0, stream>>>(x, nw, xn, d);
  // u reuses qk space (qk dead after cos_p)
  gemm_bf16_swiglu<<<dim3(h / 64, T / 128), 256, 0, stream>>>(xn, fc1t, u, T, h, d, h);
  gemm_bf16_res<<<dim3(d / 128, T / 128), 256, 0, stream>>>(u, fc2t, x, zout, T, d, h);
  // ---- EMA scan (3 passes, in place on d_out) ----
  scan1<<<dim3(NC, d / 512), 256, 0, stream>>>(zout, P, Aa, Bf, d);
  scan2<<<dim3(d / 256), 256, 0, stream>>>(zout, Ac, Hprev, d, NC);
  scan3<<<dim3(T), 256, 0, stream>>>(zout, Pfx, Hprev, d);
}